// Round 12
// baseline (33.838 us; speedup 1.0000x reference)
//
#include <hip/hip_runtime.h>
#include <hip/hip_fp16.h>
#include <math.h>

#define HH 768
#define WW 1024
#define HW (HH * WW)
#define NTAPS 5
#define F_EPS 1.1920929e-07f
#define LOG2E 1.44269504f

#define TSX  32            // tile width (pixels)
#define TSY  96            // tile height (pixels), 3 px/thread vertically
#define RAD  10            // halo radius: |sample disp| < 10 strictly for active taps
#define COLS 53            // TSX + 2*RAD + 1 (right corner)
#define ROWS 117           // TSY + 2*RAD + 1
#define TP   54            // padded LDS row stride (texels)

typedef __fp16 h2 __attribute__((ext_vector_type(2)));
typedef float  f2 __attribute__((ext_vector_type(2)));
union H2U { h2 h; unsigned u; };

__device__ __forceinline__ float fast_rcp(float v) {
    return __builtin_amdgcn_rcpf(v);
}
__device__ __forceinline__ h2 as_h2(unsigned u) { H2U t; t.u = u; return t.h; }
#define SH(v,i)    __builtin_shufflevector((v), (v), (i), (i))
#define SWAP2(v)   __builtin_shufflevector((v), (v), 1, 0)

__global__ __launch_bounds__(1024, 2) void fab_tile(
    const float* __restrict__ x,
    const float* __restrict__ tangent,
    const float* __restrict__ sigmaD,
    const float* __restrict__ sigmaR,
    float* __restrict__ out)
{
    // interleaved texel: .x = h2(100*c0[x], 100*c0[x+1]), .y = h2(254*c1, 254*c2)
    __shared__ uint2 tileT[ROWS * TP];     // 49.4 KB -> exactly 2 blocks/CU

    const int tiles_x = WW / TSX;          // 32
    const int tiles_y = HH / TSY;          // 8
    const int tpb = tiles_x * tiles_y;     // 256; grid = bs*256 = 512 = 2/CU exact
    int tid = threadIdx.x;
    int bid = blockIdx.x;
    int b = bid / tpb;
    int tq = bid - b * tpb;
    int tyi = tq / tiles_x;
    int txi = tq - tyi * tiles_x;
    int tx0 = txi * TSX, ty0 = tyi * TSY;

    const float* xb = x + (size_t)b * 3 * HW;

    // stage halo window (border-clamped -> per-sample clamping unnecessary)
    for (int cI = tid; cI < ROWS * COLS; cI += 1024) {
        int syy = cI / COLS;
        int sxx = cI - syy * COLS;
        int wx = tx0 - RAD + sxx;
        int sgx  = min(max(wx, 0), WW - 1);
        int sgx1 = min(max(wx + 1, 0), WW - 1);
        int sgy = min(max(ty0 - RAD + syy, 0), HH - 1);
        int g = sgy * WW;
        float a0v = xb[g + sgx]  * 100.0f;
        float a1v = xb[g + sgx1] * 100.0f;
        float c1v = xb[HW + g + sgx]     * 254.0f;
        float c2v = xb[2 * HW + g + sgx] * 254.0f;
        H2U pa; pa.h = __builtin_amdgcn_cvt_pkrtz(a0v, a1v);
        H2U pb; pb.h = __builtin_amdgcn_cvt_pkrtz(c1v, c2v);
        uint2 v; v.x = pa.u; v.y = pb.u;
        tileT[syy * TP + sxx] = v;
    }
    __syncthreads();

    int lx = tid & (TSX - 1);
    int ly0 = tid >> 5;                    // 0..31
    float sD = sigmaD[b], sR = sigmaR[b];
    float half_step = 2.0f * sD;
    float nD = -fast_rcp(2.0f * sD * sD + F_EPS) * LOG2E;
    float nR = -fast_rcp(2.0f * sR * sR + F_EPS) * LOG2E;
    const f2 nR2 = {nR, nR};
    const unsigned* td = (const unsigned*)tileT;

#pragma unroll
    for (int q = 0; q < 3; ++q) {
        int ly = ly0 + q * 32;
        int w = tx0 + lx, h = ty0 + ly;
        int p = h * WW + w;

        float tx = tangent[(size_t)b * 2 * HW + p];
        float ty = tangent[(size_t)b * 2 * HW + HW + p];
        float me = fmaxf(fabsf(tx), fabsf(ty));
        float ds = (me > 0.0f) ? fast_rcp(me) : 1.0f;

        float C0 = xb[p] * 100.0f;
        float C1 = xb[HW + p] * 254.0f;
        float C2 = xb[2 * HW + p] * 254.0f;
        const f2 C0p = {C0, C0};
        const f2 C1p = {C1, C1};
        const f2 C2p = {C2, C2};

        f2 normp = {0.0f, 0.0f};
        f2 a0p = {0.0f, 0.0f};
        f2 a1p = {0.0f, 0.0f};
        f2 a2p = {0.0f, 0.0f};

        int ibase_a = (RAD + ly) * TP + (RAD + lx);
        int ibase_b = ibase_a - TP - 1;

        // Gaussian recurrence in exp2 domain: kD(n) = Q^(n^2)
        float Q  = __builtin_amdgcn_exp2f(ds * ds * nD);
        float Q2 = Q * Q;
        float pw = Q;        // Q^(n^2), n=1
        float rq = Q2 * Q;   // Q^(2n+1), n=1

#pragma unroll
        for (int t = 0; t < NTAPS; ++t) {
            float itr1 = ds * (float)(2 * t + 1);
            float itr2 = ds * (float)(2 * t + 2);
            float kD1 = pw; pw *= rq; rq *= Q2;
            float kD2 = pw; pw *= rq; rq *= Q2;
            if (itr1 > half_step) continue;   // kernelD == 0 exactly
            float kernelD = kD1 + kD2;
            float itr_d = (itr1 * kD1 + itr2 * kD2) * fast_rcp(kernelD + F_EPS);
            float ox = itr_d * tx;
            float oy = itr_d * ty;

            // shared floor/frac (mirror sample reuses them)
            float fox = floorf(ox), foy = floorf(oy);
            float f_x = ox - fox,   f_y = oy - foy;
            int iox = (int)fox, ioy = (int)foy;
            int d = ioy * TP + iox;
            int i0a = ibase_a + d;
            int i0b = ibase_b - d;

            // 2 LDS instructions per sample
            uint2 Ta  = tileT[i0a];
            uint2 Tta = tileT[i0a + TP];
            unsigned Bra = td[2 * i0a + 3];
            unsigned Bba = td[2 * i0a + 2 * TP + 3];
            uint2 Tb  = tileT[i0b];
            uint2 Ttb = tileT[i0b + TP];
            unsigned Brb = td[2 * i0b + 3];
            unsigned Bbb = td[2 * i0b + 2 * TP + 3];

            // fp16 weight construction; broadcasts/swaps fold into pk op_sel
            float gxa = 1.0f - f_x, gya = 1.0f - f_y;
            h2 Wx = __builtin_amdgcn_cvt_pkrtz(gxa, f_x);   // (gx, fx)
            h2 Wy = __builtin_amdgcn_cvt_pkrtz(gya, f_y);   // (gy, fy)
            h2 Wt = Wx * SH(Wy, 0);    // (w00, w01)
            h2 Wb = Wx * SH(Wy, 1);    // (w10, w11)

            // sample a
            h2 m0a = as_h2(Ta.x) * Wt + as_h2(Tta.x) * Wb;
            float s0a = (float)m0a.x + (float)m0a.y;
            h2 s12a = as_h2(Ta.y)  * SH(Wt, 0) + as_h2(Bra) * SH(Wt, 1)
                    + as_h2(Tta.y) * SH(Wb, 0) + as_h2(Bba) * SH(Wb, 1);

            // sample b (weights are the reverse permutation)
            h2 m0b = as_h2(Tb.x) * SWAP2(Wb) + as_h2(Ttb.x) * SWAP2(Wt);
            float s0b = (float)m0b.x + (float)m0b.y;
            h2 s12b = as_h2(Tb.y)  * SH(Wb, 1) + as_h2(Brb) * SH(Wb, 0)
                    + as_h2(Ttb.y) * SH(Wt, 1) + as_h2(Bbb) * SH(Wt, 0);

            f2 s0p = {s0a, s0b};
            f2 s1p = {(float)s12a.x, (float)s12b.x};
            f2 s2p = {(float)s12a.y, (float)s12b.y};

            f2 cc0 = s0p - C0p;
            f2 cc1 = s1p - C1p;
            f2 cc2 = s2p - C2p;
            f2 e2p = cc0 * cc0 + cc1 * cc1 + cc2 * cc2;
            f2 e2n = e2p * nR2;
            f2 kEp = {__builtin_amdgcn_exp2f(e2n.x), __builtin_amdgcn_exp2f(e2n.y)};
            f2 kDp = {kernelD, kernelD};
            f2 wgtp = kEp * kDp;
            normp += wgtp;
            a0p += wgtp * s0p;
            a1p += wgtp * s1p;
            a2p += wgtp * s2p;
        }

        float norm = 1.0f + normp.x + normp.y;
        float a0 = C0 + a0p.x + a0p.y;
        float a1 = C1 + a1p.x + a1p.y;
        float a2 = C2 + a2p.x + a2p.y;

        float inv = fast_rcp(norm);
        size_t ob = (size_t)b * 3 * HW;
        out[ob + p]          = a0 * inv * 0.01f;
        out[ob + HW + p]     = a1 * inv * (1.0f / 254.0f);
        out[ob + 2 * HW + p] = a2 * inv * (1.0f / 254.0f);
    }
}

extern "C" void kernel_launch(void* const* d_in, const int* in_sizes, int n_in,
                              void* d_out, int out_size, void* d_ws, size_t ws_size,
                              hipStream_t stream) {
    const float* x = (const float*)d_in[0];
    const float* tangent = (const float*)d_in[1];
    const float* sigmaD = (const float*)d_in[2];
    const float* sigmaR = (const float*)d_in[3];
    float* out = (float*)d_out;

    int bs = in_sizes[2];           // sigmaD has one entry per batch
    int tpb = (WW / TSX) * (HH / TSY);
    fab_tile<<<bs * tpb, 1024, 0, stream>>>(x, tangent, sigmaD, sigmaR, out);
}

// Round 13
// 31.386 us; speedup vs baseline: 1.0781x; 1.0781x over previous
//
#include <hip/hip_runtime.h>
#include <hip/hip_fp16.h>
#include <math.h>

#define HH 768
#define WW 1024
#define HW (HH * WW)
#define NTAPS 5
#define F_EPS 1.1920929e-07f
#define LOG2E 1.44269504f

#define TS   32            // tile size (pixels), 1 px/thread, 1536 blocks
#define RAD  10            // halo radius: |sample disp| < 10 strictly
#define ROWS 53            // staged rows
#define COLS 53            // staged cols
#define TP   54            // padded LDS row stride (texels)

typedef __fp16 h2 __attribute__((ext_vector_type(2)));
typedef float  f2 __attribute__((ext_vector_type(2)));
union H2U { h2 h; unsigned u; };

__device__ __forceinline__ float fast_rcp(float v) {
    return __builtin_amdgcn_rcpf(v);
}
__device__ __forceinline__ h2 as_h2(unsigned u) { H2U t; t.u = u; return t.h; }
#define SH(v,i)    __builtin_shufflevector((v), (v), (i), (i))
#define SWAP2(v)   __builtin_shufflevector((v), (v), 1, 0)

__global__ __launch_bounds__(1024, 2) void fab_tile(
    const float* __restrict__ x,
    const float* __restrict__ tangent,
    const float* __restrict__ sigmaD,
    const float* __restrict__ sigmaR,
    float* __restrict__ out)
{
    // interleaved texel: .x = h2(100*c0[x], 100*c0[x+1]), .y = h2(254*c1, 254*c2)
    __shared__ uint2 tileT[ROWS * TP];

    const int tiles_x = WW / TS;           // 32
    const int tiles_y = HH / TS;           // 24
    const int tpb = tiles_x * tiles_y;     // 768; grid = 1536 blocks (good balance)
    int tid = threadIdx.x;
    int bid = blockIdx.x;
    int b = bid / tpb;
    int tq = bid - b * tpb;
    int tyi = tq / tiles_x;
    int txi = tq - tyi * tiles_x;
    int tx0 = txi * TS, ty0 = tyi * TS;

    const float* xb = x + (size_t)b * 3 * HW;

    // stage halo window (border-clamped -> per-sample clamping unnecessary)
    for (int cI = tid; cI < ROWS * COLS; cI += 1024) {
        int syy = cI / COLS;
        int sxx = cI - syy * COLS;
        int wx = tx0 - RAD + sxx;
        int sgx  = min(max(wx, 0), WW - 1);
        int sgx1 = min(max(wx + 1, 0), WW - 1);
        int sgy = min(max(ty0 - RAD + syy, 0), HH - 1);
        int g = sgy * WW;
        float a0v = xb[g + sgx]  * 100.0f;
        float a1v = xb[g + sgx1] * 100.0f;
        float c1v = xb[HW + g + sgx]     * 254.0f;
        float c2v = xb[2 * HW + g + sgx] * 254.0f;
        H2U pa; pa.h = __builtin_amdgcn_cvt_pkrtz(a0v, a1v);
        H2U pb; pb.h = __builtin_amdgcn_cvt_pkrtz(c1v, c2v);
        uint2 v; v.x = pa.u; v.y = pb.u;
        tileT[syy * TP + sxx] = v;
    }
    __syncthreads();

    int lx = tid & (TS - 1);
    int ly = tid >> 5;
    int w = tx0 + lx, h = ty0 + ly;
    int p = h * WW + w;

    float tx = tangent[(size_t)b * 2 * HW + p];
    float ty = tangent[(size_t)b * 2 * HW + HW + p];
    float me = fmaxf(fabsf(tx), fabsf(ty));
    float ds = (me > 0.0f) ? fast_rcp(me) : 1.0f;
    float sD = sigmaD[b], sR = sigmaR[b];
    float half_step = 2.0f * sD;
    float nD = -fast_rcp(2.0f * sD * sD + F_EPS) * LOG2E;
    float nR = -fast_rcp(2.0f * sR * sR + F_EPS) * LOG2E;
    const f2 nR2 = {nR, nR};
    const unsigned* td = (const unsigned*)tileT;

    float C0 = xb[p] * 100.0f;
    float C1 = xb[HW + p] * 254.0f;
    float C2 = xb[2 * HW + p] * 254.0f;
    const f2 C0p = {C0, C0};
    const f2 C1p = {C1, C1};
    const f2 C2p = {C2, C2};

    f2 normp = {0.0f, 0.0f};
    f2 a0p = {0.0f, 0.0f};
    f2 a1p = {0.0f, 0.0f};
    f2 a2p = {0.0f, 0.0f};

    int ibase_a = (RAD + ly) * TP + (RAD + lx);
    int ibase_b = ibase_a - TP - 1;

    // Gaussian recurrence in exp2 domain: kD(n) = Q^(n^2)
    float Q  = __builtin_amdgcn_exp2f(ds * ds * nD);
    float Q2 = Q * Q;
    float pw = Q;        // Q^(n^2), n=1
    float rq = Q2 * Q;   // Q^(2n+1), n=1

#pragma unroll
    for (int t = 0; t < NTAPS; ++t) {
        float itr1 = ds * (float)(2 * t + 1);
        float itr2 = ds * (float)(2 * t + 2);
        float kD1 = pw; pw *= rq; rq *= Q2;
        float kD2 = pw; pw *= rq; rq *= Q2;
        if (itr1 > half_step) continue;   // kernelD == 0 exactly -> no contribution
        float kernelD = kD1 + kD2;
        float itr_d = (itr1 * kD1 + itr2 * kD2) * fast_rcp(kernelD + F_EPS);
        float ox = itr_d * tx;
        float oy = itr_d * ty;

        // shared floor/frac: floor(w+ox) = w+floor(ox); floor(w-ox) = w-floor(ox)-1
        float fox = floorf(ox), foy = floorf(oy);
        float f_x = ox - fox,   f_y = oy - foy;
        int iox = (int)fox, ioy = (int)foy;
        int d = ioy * TP + iox;
        int i0a = ibase_a + d;
        int i0b = ibase_b - d;

        // 2 LDS instructions per sample:
        //   ds_read2_b64 {0, TP}    -> texels (i), (i+TP)
        //   ds_read2_b32 {3, 2TP+3} -> right-corner B's
        uint2 Ta  = tileT[i0a];
        uint2 Tta = tileT[i0a + TP];
        unsigned Bra = td[2 * i0a + 3];
        unsigned Bba = td[2 * i0a + 2 * TP + 3];
        uint2 Tb  = tileT[i0b];
        uint2 Ttb = tileT[i0b + TP];
        unsigned Brb = td[2 * i0b + 3];
        unsigned Bbb = td[2 * i0b + 2 * TP + 3];

        // fp16 weight construction; broadcasts/swaps fold into pk op_sel
        float gxa = 1.0f - f_x, gya = 1.0f - f_y;
        h2 Wx = __builtin_amdgcn_cvt_pkrtz(gxa, f_x);   // (gx, fx)
        h2 Wy = __builtin_amdgcn_cvt_pkrtz(gya, f_y);   // (gy, fy)
        h2 Wt = Wx * SH(Wy, 0);    // (w00, w01)
        h2 Wb = Wx * SH(Wy, 1);    // (w10, w11)

        // sample a
        h2 m0a = as_h2(Ta.x) * Wt + as_h2(Tta.x) * Wb;
        float s0a = (float)m0a.x + (float)m0a.y;
        h2 s12a = as_h2(Ta.y)  * SH(Wt, 0) + as_h2(Bra) * SH(Wt, 1)
                + as_h2(Tta.y) * SH(Wb, 0) + as_h2(Bba) * SH(Wb, 1);

        // sample b (weights are the reverse permutation)
        h2 m0b = as_h2(Tb.x) * SWAP2(Wb) + as_h2(Ttb.x) * SWAP2(Wt);
        float s0b = (float)m0b.x + (float)m0b.y;
        h2 s12b = as_h2(Tb.y)  * SH(Wb, 1) + as_h2(Brb) * SH(Wb, 0)
                + as_h2(Ttb.y) * SH(Wt, 1) + as_h2(Bbb) * SH(Wt, 0);

        f2 s0p = {s0a, s0b};
        f2 s1p = {(float)s12a.x, (float)s12b.x};
        f2 s2p = {(float)s12a.y, (float)s12b.y};

        f2 cc0 = s0p - C0p;
        f2 cc1 = s1p - C1p;
        f2 cc2 = s2p - C2p;
        f2 e2p = cc0 * cc0 + cc1 * cc1 + cc2 * cc2;
        f2 e2n = e2p * nR2;
        f2 kEp = {__builtin_amdgcn_exp2f(e2n.x), __builtin_amdgcn_exp2f(e2n.y)};
        f2 kDp = {kernelD, kernelD};
        f2 wgtp = kEp * kDp;
        normp += wgtp;
        a0p += wgtp * s0p;
        a1p += wgtp * s1p;
        a2p += wgtp * s2p;
    }

    float norm = 1.0f + normp.x + normp.y;
    float a0 = C0 + a0p.x + a0p.y;
    float a1 = C1 + a1p.x + a1p.y;
    float a2 = C2 + a2p.x + a2p.y;

    float inv = fast_rcp(norm);
    size_t ob = (size_t)b * 3 * HW;
    out[ob + p]          = a0 * inv * 0.01f;
    out[ob + HW + p]     = a1 * inv * (1.0f / 254.0f);
    out[ob + 2 * HW + p] = a2 * inv * (1.0f / 254.0f);
}

extern "C" void kernel_launch(void* const* d_in, const int* in_sizes, int n_in,
                              void* d_out, int out_size, void* d_ws, size_t ws_size,
                              hipStream_t stream) {
    const float* x = (const float*)d_in[0];
    const float* tangent = (const float*)d_in[1];
    const float* sigmaD = (const float*)d_in[2];
    const float* sigmaR = (const float*)d_in[3];
    float* out = (float*)d_out;

    int bs = in_sizes[2];           // sigmaD has one entry per batch
    int tpb = (WW / TS) * (HH / TS);
    fab_tile<<<bs * tpb, 1024, 0, stream>>>(x, tangent, sigmaD, sigmaR, out);
}